// Round 8
// baseline (293.528 us; speedup 1.0000x reference)
//
#include <hip/hip_runtime.h>
#include <cstdint>
#include <cstddef>

#define NHEAD 8
#define SLEN 1024

typedef __bf16 bf16x8 __attribute__((ext_vector_type(8)));
typedef float f32x4 __attribute__((ext_vector_type(4)));

__device__ inline unsigned short f2bf(float f) {
    union { float f; unsigned int u; } v; v.f = f;
    unsigned int u = v.u;
    unsigned int rounded = u + 0x7fffu + ((u >> 16) & 1u);
    return (unsigned short)(rounded >> 16);
}

__device__ inline unsigned int pack2(float a, float b) {
    return (unsigned int)f2bf(a) | ((unsigned int)f2bf(b) << 16);
}

__device__ inline uint4 cvt8(const float* __restrict__ p) {
    float4 a = *reinterpret_cast<const float4*>(p);
    float4 b = *reinterpret_cast<const float4*>(p + 4);
    uint4 r;
    r.x = pack2(a.x, a.y);
    r.y = pack2(a.z, a.w);
    r.z = pack2(b.x, b.y);
    r.w = pack2(b.z, b.w);
    return r;
}

// ---------------- mask bit-packing ----------------
__global__ __launch_bounds__(256) void pack_mask(
    const float* __restrict__ mask, unsigned long long* __restrict__ bits)
{
    int wid = (blockIdx.x * 256 + threadIdx.x) >> 6;
    int lane = threadIdx.x & 63;
    for (int s = 0; s < 4; s++) {
        size_t seg = (size_t)wid * 4 + s;
        float mv = mask[seg * 64 + lane];
        unsigned long long bb = __ballot(mv != 0.0f);
        if (lane == 0) bits[seg] = bb;
    }
}

// ---------------- f32 -> bf16 pre-cast (X + 4 weights) ----------------
__global__ __launch_bounds__(256) void cast_all(
    const float* __restrict__ X,
    const float* __restrict__ wq, const float* __restrict__ wk,
    const float* __restrict__ wv, const float* __restrict__ wo,
    unsigned short* __restrict__ Xb, unsigned short* __restrict__ Wc)
{
    int y = blockIdx.y;
    const float* src;
    unsigned short* dst;
    int n;
    if (y == 0) { src = X;  dst = Xb; n = 8192 * 512; }
    else {
        src = (y == 1) ? wq : (y == 2) ? wk : (y == 3) ? wv : wo;
        dst = Wc + (size_t)(y - 1) * 262144;
        n = 262144;
    }
    int i = (blockIdx.x * 256 + threadIdx.x) * 8;
    if (i + 8 <= n) {
        uint4 v = cvt8(src + i);
        *reinterpret_cast<uint4*>(dst + i) = v;
    }
}

// ---------------- fused QKV projection GEMM (bf16 in) ----------------
__global__ __launch_bounds__(256) void qkv_gemm(
    const unsigned short* __restrict__ Xb,
    const unsigned short* __restrict__ Wc,
    const float* __restrict__ bq, const float* __restrict__ bk,
    const float* __restrict__ bv,
    unsigned short* __restrict__ Qb, unsigned short* __restrict__ Kb,
    unsigned short* __restrict__ Vtb)
{
    __shared__ unsigned short As[17408];
    unsigned short* Bs = As + 128 * 40;
    const int tid = threadIdx.x;
    const int w = tid >> 6, lane = tid & 63, l15 = lane & 15, quad = lane >> 4;
    const int wm = w & 1, wn = w >> 1;
    const int r0 = blockIdx.x * 128;
    const int ytile = blockIdx.y;
    const int c0 = ytile * 128;
    const unsigned short* Wsel = Wc + (size_t)(ytile >> 2) * 262144;
    const int cw = c0 & 511;

    f32x4 zero = {0.0f, 0.0f, 0.0f, 0.0f};
    f32x4 acc[4][4];
    for (int i = 0; i < 4; i++)
        for (int j = 0; j < 4; j++) acc[i][j] = zero;

    const int srow = tid >> 1;
    const int scol = (tid & 1) * 16;

    for (int k0 = 0; k0 < 512; k0 += 32) {
        const unsigned short* pa = Xb + (size_t)(r0 + srow) * 512 + k0 + scol;
        const unsigned short* pb = Wsel + (size_t)(cw + srow) * 512 + k0 + scol;
        uint4 a0 = *reinterpret_cast<const uint4*>(pa);
        uint4 a1 = *reinterpret_cast<const uint4*>(pa + 8);
        uint4 b0 = *reinterpret_cast<const uint4*>(pb);
        uint4 b1 = *reinterpret_cast<const uint4*>(pb + 8);
        *reinterpret_cast<uint4*>(As + srow * 40 + scol) = a0;
        *reinterpret_cast<uint4*>(As + srow * 40 + scol + 8) = a1;
        *reinterpret_cast<uint4*>(Bs + srow * 40 + scol) = b0;
        *reinterpret_cast<uint4*>(Bs + srow * 40 + scol + 8) = b1;
        __syncthreads();
        bf16x8 af[4], bfr[4];
        for (int mi = 0; mi < 4; mi++)
            af[mi] = *reinterpret_cast<const bf16x8*>(As + (wm * 64 + mi * 16 + l15) * 40 + quad * 8);
        for (int ni = 0; ni < 4; ni++)
            bfr[ni] = *reinterpret_cast<const bf16x8*>(Bs + (wn * 64 + ni * 16 + l15) * 40 + quad * 8);
        for (int mi = 0; mi < 4; mi++)
            for (int ni = 0; ni < 4; ni++)
                acc[mi][ni] = __builtin_amdgcn_mfma_f32_16x16x32_bf16(af[mi], bfr[ni], acc[mi][ni], 0, 0, 0);
        __syncthreads();
    }

    const int bb = r0 >> 10;
    const int s0 = r0 & 1023;

    if (ytile < 8) {
        const bool isQ = (ytile < 4);
        const float* bias = isQ ? bq : bk;
        unsigned short* dst = isQ ? Qb : Kb;
        const float scale = isQ ? 0.125f : 1.0f;
        const int h0 = cw >> 6;
        for (int mi = 0; mi < 4; mi++) {
            for (int ni = 0; ni < 4; ni++) {
                int col = wn * 64 + ni * 16 + l15;
                float bsv = bias[cw + col];
                for (int r = 0; r < 4; r++) {
                    int s_local = wm * 64 + mi * 16 + quad * 4 + r;
                    As[s_local * 136 + col] = f2bf((acc[mi][ni][r] + bsv) * scale);
                }
            }
        }
        __syncthreads();
        for (int p = 0; p < 2; p++) {
            size_t base = (((size_t)(bb * NHEAD + h0 + p)) << 10) + s0;
            for (int i = 0; i < 4; i++) {
                int flat = i * 256 + tid;
                int row = flat >> 3;
                int ch = flat & 7;
                uint4 vv = *reinterpret_cast<const uint4*>(As + row * 136 + p * 64 + ch * 8);
                *reinterpret_cast<uint4*>(dst + (base + row) * 64 + ch * 8) = vv;
            }
        }
    } else {
        const int h_base = (c0 - 1024) >> 6;
        for (int p = 0; p < 2; p++) {
            __syncthreads();
            if (wn == p) {
                for (int mi = 0; mi < 4; mi++) {
                    for (int ni = 0; ni < 4; ni++) {
                        int d_local = ni * 16 + l15;
                        float bias = bv[(h_base + p) * 64 + d_local];
                        for (int r = 0; r < 4; r++) {
                            int s_local = wm * 64 + mi * 16 + quad * 4 + r;
                            As[d_local * 136 + s_local] = f2bf(acc[mi][ni][r] + bias);
                        }
                    }
                }
            }
            __syncthreads();
            int sidx = (tid & 15) * 8;
            int drow = tid >> 4;
            for (int dg = 0; dg < 4; dg++) {
                int d = dg * 16 + drow;
                size_t dst = ((size_t)(bb * NHEAD + h_base + p) * 64 + d) * 1024 + s0;
                uint4 vv = *reinterpret_cast<const uint4*>(As + d * 136 + sidx);
                *reinterpret_cast<uint4*>(Vtb + dst + sidx) = vv;
            }
        }
    }
}

// ---------------- flash attention: transposed MFMAs + K-split x2 ----------------
// Block = 4 waves covering 32 q-rows: wave (qsub = w>>1, khalf = w&1) handles
// q-rows [qt*32 + qsub*16, +16) over keys [khalf*512, +512). 8192 waves total
// (2x R7) -> 32 waves/CU; per-wave serial span halves to 8 k-tiles.
// Wave pairs merge via flash-decoding rule through LDS (3 barriers, O(1)).
__global__ __launch_bounds__(256) void attn_kernel(
    const unsigned short* __restrict__ Qb,
    const unsigned short* __restrict__ Kb,
    const unsigned short* __restrict__ Vtb,
    const unsigned long long* __restrict__ Mbits,
    unsigned short* __restrict__ Ob)
{
    __shared__ float Smerge[2560];   // 10240 B; [0,9216)B = P^T regions; merge reuses all

    const int tid = threadIdx.x;
    const int w = tid >> 6, lane = tid & 63, l15 = lane & 15, quad = lane >> 4;
    const int qsub = w >> 1, khalf = w & 1;
    const int qt = blockIdx.x, h = blockIdx.y, b = blockIdx.z;
    const int q = qt * 32 + qsub * 16 + l15;       // this lane's query row
    const size_t bh = (size_t)(b * NHEAD + h);
    const unsigned short* Qg = Qb + bh * SLEN * 64;
    const unsigned short* Kg = Kb + bh * SLEN * 64;
    const unsigned short* Vg = Vtb + bh * 64 * SLEN;
    const unsigned long long* mrow = Mbits + ((size_t)b * SLEN + q) * 16;
    __bf16* Prow = (__bf16*)Smerge + (size_t)(w * 16 + l15) * 72;

    // Q B-frag: n = q = l15, k = quad*8+j
    bf16x8 bq0 = *reinterpret_cast<const bf16x8*>(Qg + (size_t)q * 64 + quad * 8);
    bf16x8 bq1 = *reinterpret_cast<const bf16x8*>(Qg + (size_t)q * 64 + 32 + quad * 8);

    float m_i = -3.0e38f, l_i = 0.0f;
    f32x4 zero = {0.0f, 0.0f, 0.0f, 0.0f};
    f32x4 Oacc[4];
    for (int nd = 0; nd < 4; nd++) Oacc[nd] = zero;

    const int kt0 = khalf * 8;
    for (int kt2 = 0; kt2 < 8; kt2++) {
        const int kt = kt0 + kt2;
        const int k0 = kt * 64;

        unsigned long long mw = mrow[kt] >> (quad * 4);
        unsigned int mlo = (unsigned int)mw;
        unsigned int mhi = (unsigned int)(mw >> 32);

        // S^T = K Q^T : A = K (m = key), B = Q (n = q)
        f32x4 st[4];
        for (int ni = 0; ni < 4; ni++) {
            const unsigned short* kp = Kg + (size_t)(k0 + ni * 16 + l15) * 64 + quad * 8;
            bf16x8 ka0 = *reinterpret_cast<const bf16x8*>(kp);
            bf16x8 ka1 = *reinterpret_cast<const bf16x8*>(kp + 32);
            f32x4 z = zero;
            z = __builtin_amdgcn_mfma_f32_16x16x32_bf16(ka0, bq0, z, 0, 0, 0);
            z = __builtin_amdgcn_mfma_f32_16x16x32_bf16(ka1, bq1, z, 0, 0, 0);
            st[ni] = z;
        }
        for (int r = 0; r < 4; r++) {
            st[0][r] = ((mlo >> r) & 1u)        ? -1.0e7f : st[0][r];
            st[1][r] = ((mlo >> (16 + r)) & 1u) ? -1.0e7f : st[1][r];
            st[2][r] = ((mhi >> r) & 1u)        ? -1.0e7f : st[2][r];
            st[3][r] = ((mhi >> (16 + r)) & 1u) ? -1.0e7f : st[3][r];
        }
        float t01 = fmaxf(fmaxf(st[0][0], st[0][1]), fmaxf(st[0][2], st[0][3]));
        float t23 = fmaxf(fmaxf(st[1][0], st[1][1]), fmaxf(st[1][2], st[1][3]));
        float t45 = fmaxf(fmaxf(st[2][0], st[2][1]), fmaxf(st[2][2], st[2][3]));
        float t67 = fmaxf(fmaxf(st[3][0], st[3][1]), fmaxf(st[3][2], st[3][3]));
        float t = fmaxf(fmaxf(t01, t23), fmaxf(t45, t67));
        t = fmaxf(t, __shfl_xor(t, 16));
        t = fmaxf(t, __shfl_xor(t, 32));
        float mnew = fmaxf(m_i, t);
        float alpha = __expf(m_i - mnew);
        m_i = mnew;

        float psum = 0.0f;
        for (int ni = 0; ni < 4; ni++) {
            float p0 = __expf(st[ni][0] - mnew);
            float p1 = __expf(st[ni][1] - mnew);
            float p2 = __expf(st[ni][2] - mnew);
            float p3 = __expf(st[ni][3] - mnew);
            psum += (p0 + p1) + (p2 + p3);
            uint2 pk;
            pk.x = pack2(p0, p1);
            pk.y = pack2(p2, p3);
            *reinterpret_cast<uint2*>(Prow + ni * 16 + quad * 4) = pk;
        }
        psum += __shfl_xor(psum, 16);
        psum += __shfl_xor(psum, 32);
        l_i = l_i * alpha + psum;
        for (int nd = 0; nd < 4; nd++)
            for (int r = 0; r < 4; r++)
                Oacc[nd][r] *= alpha;

        bf16x8 bp0 = *reinterpret_cast<const bf16x8*>(Prow + quad * 8);
        bf16x8 bp1 = *reinterpret_cast<const bf16x8*>(Prow + 32 + quad * 8);
        for (int nd = 0; nd < 4; nd++) {
            const unsigned short* vp = Vg + (size_t)(nd * 16 + l15) * SLEN + k0 + quad * 8;
            bf16x8 va0 = *reinterpret_cast<const bf16x8*>(vp);
            bf16x8 va1 = *reinterpret_cast<const bf16x8*>(vp + 32);
            Oacc[nd] = __builtin_amdgcn_mfma_f32_16x16x32_bf16(va0, bp0, Oacc[nd], 0, 0, 0);
            Oacc[nd] = __builtin_amdgcn_mfma_f32_16x16x32_bf16(va1, bp1, Oacc[nd], 0, 0, 0);
        }
    }

    // ---- flash-decoding merge of the wave pair (khalf 0 <-> 1) ----
    float* ML = Smerge;            // [w][lane][2]  (512 floats)
    float* OB = Smerge + 512;      // [qsub][(nd*4+r)][lane] (2048 floats, conflict-free)
    __syncthreads();               // all waves done with P^T regions
    ML[(w * 64 + lane) * 2 + 0] = m_i;
    ML[(w * 64 + lane) * 2 + 1] = l_i;
    __syncthreads();
    float mp = ML[((w ^ 1) * 64 + lane) * 2 + 0];
    float lp = ML[((w ^ 1) * 64 + lane) * 2 + 1];
    float m01 = fmaxf(m_i, mp);
    float e  = __expf(m_i - m01);
    float ep = __expf(mp - m01);
    float l01 = l_i * e + lp * ep;

    if (khalf == 1) {
        for (int nd = 0; nd < 4; nd++)
            for (int r = 0; r < 4; r++)
                OB[qsub * 1024 + (nd * 4 + r) * 64 + lane] = Oacc[nd][r] * e;
    }
    __syncthreads();
    if (khalf == 0) {
        float inv = 1.0f / l01;
        for (int nd = 0; nd < 4; nd++) {
            float o0 = (Oacc[nd][0] * e + OB[qsub * 1024 + (nd * 4 + 0) * 64 + lane]) * inv;
            float o1 = (Oacc[nd][1] * e + OB[qsub * 1024 + (nd * 4 + 1) * 64 + lane]) * inv;
            float o2 = (Oacc[nd][2] * e + OB[qsub * 1024 + (nd * 4 + 2) * 64 + lane]) * inv;
            float o3 = (Oacc[nd][3] * e + OB[qsub * 1024 + (nd * 4 + 3) * 64 + lane]) * inv;
            uint2 o;
            o.x = pack2(o0, o1);
            o.y = pack2(o2, o3);
            *reinterpret_cast<uint2*>(Ob + ((size_t)(b * SLEN + q)) * 512 + h * 64 + nd * 16 + quad * 4) = o;
        }
    }
}

// ---------------- output projection GEMM (bf16 in, f32 out) ----------------
__global__ __launch_bounds__(256) void out_gemm(
    const unsigned short* __restrict__ Ob,
    const unsigned short* __restrict__ Wob,
    const float* __restrict__ bo,
    float* __restrict__ out)
{
    __shared__ unsigned short As[128 * 40];
    __shared__ unsigned short Bs[128 * 40];
    const int tid = threadIdx.x;
    const int w = tid >> 6, lane = tid & 63, l15 = lane & 15, quad = lane >> 4;
    const int wm = w & 1, wn = w >> 1;
    const int r0 = blockIdx.x * 128;
    const int c0 = blockIdx.y * 128;

    f32x4 zero = {0.0f, 0.0f, 0.0f, 0.0f};
    f32x4 acc[4][4];
    for (int i = 0; i < 4; i++)
        for (int j = 0; j < 4; j++) acc[i][j] = zero;

    const int srow = tid >> 1;
    const int scol = (tid & 1) * 16;

    for (int k0 = 0; k0 < 512; k0 += 32) {
        const unsigned short* pa = Ob + (size_t)(r0 + srow) * 512 + k0 + scol;
        const unsigned short* pb = Wob + (size_t)(c0 + srow) * 512 + k0 + scol;
        uint4 a0 = *reinterpret_cast<const uint4*>(pa);
        uint4 a1 = *reinterpret_cast<const uint4*>(pa + 8);
        uint4 b0 = *reinterpret_cast<const uint4*>(pb);
        uint4 b1 = *reinterpret_cast<const uint4*>(pb + 8);
        *reinterpret_cast<uint4*>(As + srow * 40 + scol) = a0;
        *reinterpret_cast<uint4*>(As + srow * 40 + scol + 8) = a1;
        *reinterpret_cast<uint4*>(Bs + srow * 40 + scol) = b0;
        *reinterpret_cast<uint4*>(Bs + srow * 40 + scol + 8) = b1;
        __syncthreads();
        bf16x8 af[4], bfr[4];
        for (int mi = 0; mi < 4; mi++)
            af[mi] = *reinterpret_cast<const bf16x8*>(As + (wm * 64 + mi * 16 + l15) * 40 + quad * 8);
        for (int ni = 0; ni < 4; ni++)
            bfr[ni] = *reinterpret_cast<const bf16x8*>(Bs + (wn * 64 + ni * 16 + l15) * 40 + quad * 8);
        for (int mi = 0; mi < 4; mi++)
            for (int ni = 0; ni < 4; ni++)
                acc[mi][ni] = __builtin_amdgcn_mfma_f32_16x16x32_bf16(af[mi], bfr[ni], acc[mi][ni], 0, 0, 0);
        __syncthreads();
    }

    for (int mi = 0; mi < 4; mi++) {
        int grow_base = r0 + wm * 64 + mi * 16 + quad * 4;
        for (int ni = 0; ni < 4; ni++) {
            int gcol = c0 + wn * 64 + ni * 16 + l15;
            float bias = bo[gcol];
            for (int r = 0; r < 4; r++) {
                int grow = grow_base + r;
                out[(size_t)grow * 512 + gcol] = acc[mi][ni][r] + bias;
            }
        }
    }
}

extern "C" void kernel_launch(void* const* d_in, const int* in_sizes, int n_in,
                              void* d_out, int out_size, void* d_ws, size_t ws_size,
                              hipStream_t stream) {
    (void)in_sizes; (void)n_in; (void)out_size; (void)ws_size;
    const float* x    = (const float*)d_in[0];
    const float* mask = (const float*)d_in[1];
    const float* wq   = (const float*)d_in[2];
    const float* bq   = (const float*)d_in[3];
    const float* wk   = (const float*)d_in[4];
    const float* bk   = (const float*)d_in[5];
    const float* wv   = (const float*)d_in[6];
    const float* bv   = (const float*)d_in[7];
    const float* wo   = (const float*)d_in[8];
    const float* bo   = (const float*)d_in[9];
    float* out = (float*)d_out;

    char* ws = (char*)d_ws;
    unsigned short* Qb   = (unsigned short*)(ws);                  // 8 MiB
    unsigned short* Kb   = (unsigned short*)(ws + 8388608);        // 8 MiB
    unsigned short* Vtb  = (unsigned short*)(ws + 16777216);       // 8 MiB
    unsigned short* XO   = (unsigned short*)(ws + 25165824);       // 8 MiB: Xb then Obuf
    unsigned short* Wc   = (unsigned short*)(ws + 33554432);       // 2 MiB
    unsigned long long* Mbits = (unsigned long long*)(ws + 35651584); // 1 MiB

    pack_mask<<<8192, 256, 0, stream>>>(mask, Mbits);
    cast_all<<<dim3(2048, 5), 256, 0, stream>>>(x, wq, wk, wv, wo, XO, Wc);
    qkv_gemm<<<dim3(64, 12), 256, 0, stream>>>(XO, Wc, bq, bk, bv, Qb, Kb, Vtb);
    attn_kernel<<<dim3(32, 8, 8), 256, 0, stream>>>(Qb, Kb, Vtb, Mbits, XO /*Obuf*/);
    out_gemm<<<dim3(64, 4), 256, 0, stream>>>(XO /*Obuf*/, Wc + 3 * 262144, bo, out);
}

// Round 9
// 286.779 us; speedup vs baseline: 1.0235x; 1.0235x over previous
//
#include <hip/hip_runtime.h>
#include <cstdint>
#include <cstddef>

#define NHEAD 8
#define SLEN 1024

typedef __bf16 bf16x8 __attribute__((ext_vector_type(8)));
typedef float f32x4 __attribute__((ext_vector_type(4)));

__device__ inline unsigned short f2bf(float f) {
    union { float f; unsigned int u; } v; v.f = f;
    unsigned int u = v.u;
    unsigned int rounded = u + 0x7fffu + ((u >> 16) & 1u);
    return (unsigned short)(rounded >> 16);
}

__device__ inline unsigned int pack2(float a, float b) {
    return (unsigned int)f2bf(a) | ((unsigned int)f2bf(b) << 16);
}

__device__ inline uint4 cvt8(const float* __restrict__ p) {
    float4 a = *reinterpret_cast<const float4*>(p);
    float4 b = *reinterpret_cast<const float4*>(p + 4);
    uint4 r;
    r.x = pack2(a.x, a.y);
    r.y = pack2(a.z, a.w);
    r.z = pack2(b.x, b.y);
    r.w = pack2(b.z, b.w);
    return r;
}

// ---------------- mask bit-packing ----------------
__global__ __launch_bounds__(256) void pack_mask(
    const float* __restrict__ mask, unsigned long long* __restrict__ bits)
{
    int wid = (blockIdx.x * 256 + threadIdx.x) >> 6;
    int lane = threadIdx.x & 63;
    for (int s = 0; s < 4; s++) {
        size_t seg = (size_t)wid * 4 + s;
        float mv = mask[seg * 64 + lane];
        unsigned long long bb = __ballot(mv != 0.0f);
        if (lane == 0) bits[seg] = bb;
    }
}

// ---------------- f32 -> bf16 pre-cast (X + 4 weights) ----------------
__global__ __launch_bounds__(256) void cast_all(
    const float* __restrict__ X,
    const float* __restrict__ wq, const float* __restrict__ wk,
    const float* __restrict__ wv, const float* __restrict__ wo,
    unsigned short* __restrict__ Xb, unsigned short* __restrict__ Wc)
{
    int y = blockIdx.y;
    const float* src;
    unsigned short* dst;
    int n;
    if (y == 0) { src = X;  dst = Xb; n = 8192 * 512; }
    else {
        src = (y == 1) ? wq : (y == 2) ? wk : (y == 3) ? wv : wo;
        dst = Wc + (size_t)(y - 1) * 262144;
        n = 262144;
    }
    int i = (blockIdx.x * 256 + threadIdx.x) * 8;
    if (i + 8 <= n) {
        uint4 v = cvt8(src + i);
        *reinterpret_cast<uint4*>(dst + i) = v;
    }
}

// ---------------- fused QKV projection GEMM (bf16 in, BK=64) ----------------
__global__ __launch_bounds__(256) void qkv_gemm(
    const unsigned short* __restrict__ Xb,
    const unsigned short* __restrict__ Wc,
    const float* __restrict__ bq, const float* __restrict__ bk,
    const float* __restrict__ bv,
    unsigned short* __restrict__ Qb, unsigned short* __restrict__ Kb,
    unsigned short* __restrict__ Vtb)
{
    __shared__ unsigned short As[2 * 128 * 72];   // 36864 B; epilogue reuses as 128x136
    unsigned short* Bs = As + 128 * 72;
    const int tid = threadIdx.x;
    const int w = tid >> 6, lane = tid & 63, l15 = lane & 15, quad = lane >> 4;
    const int wm = w & 1, wn = w >> 1;
    const int r0 = blockIdx.x * 128;
    const int ytile = blockIdx.y;
    const int c0 = ytile * 128;
    const unsigned short* Wsel = Wc + (size_t)(ytile >> 2) * 262144;
    const int cw = c0 & 511;

    f32x4 zero = {0.0f, 0.0f, 0.0f, 0.0f};
    f32x4 acc[4][4];
    for (int i = 0; i < 4; i++)
        for (int j = 0; j < 4; j++) acc[i][j] = zero;

    const int srow = tid >> 1;            // 0..127
    const int scol = (tid & 1) * 32;      // 0 or 32

    for (int k0 = 0; k0 < 512; k0 += 64) {
        const unsigned short* pa = Xb + (size_t)(r0 + srow) * 512 + k0 + scol;
        const unsigned short* pb = Wsel + (size_t)(cw + srow) * 512 + k0 + scol;
        uint4 a0 = *reinterpret_cast<const uint4*>(pa);
        uint4 a1 = *reinterpret_cast<const uint4*>(pa + 8);
        uint4 a2 = *reinterpret_cast<const uint4*>(pa + 16);
        uint4 a3 = *reinterpret_cast<const uint4*>(pa + 24);
        uint4 b0 = *reinterpret_cast<const uint4*>(pb);
        uint4 b1 = *reinterpret_cast<const uint4*>(pb + 8);
        uint4 b2 = *reinterpret_cast<const uint4*>(pb + 16);
        uint4 b3 = *reinterpret_cast<const uint4*>(pb + 24);
        unsigned short* wa = As + srow * 72 + scol;
        unsigned short* wb = Bs + srow * 72 + scol;
        *reinterpret_cast<uint4*>(wa) = a0;
        *reinterpret_cast<uint4*>(wa + 8) = a1;
        *reinterpret_cast<uint4*>(wa + 16) = a2;
        *reinterpret_cast<uint4*>(wa + 24) = a3;
        *reinterpret_cast<uint4*>(wb) = b0;
        *reinterpret_cast<uint4*>(wb + 8) = b1;
        *reinterpret_cast<uint4*>(wb + 16) = b2;
        *reinterpret_cast<uint4*>(wb + 24) = b3;
        __syncthreads();
        for (int kc = 0; kc < 64; kc += 32) {
            bf16x8 af[4], bfr[4];
            for (int mi = 0; mi < 4; mi++)
                af[mi] = *reinterpret_cast<const bf16x8*>(As + (wm * 64 + mi * 16 + l15) * 72 + kc + quad * 8);
            for (int ni = 0; ni < 4; ni++)
                bfr[ni] = *reinterpret_cast<const bf16x8*>(Bs + (wn * 64 + ni * 16 + l15) * 72 + kc + quad * 8);
            for (int mi = 0; mi < 4; mi++)
                for (int ni = 0; ni < 4; ni++)
                    acc[mi][ni] = __builtin_amdgcn_mfma_f32_16x16x32_bf16(af[mi], bfr[ni], acc[mi][ni], 0, 0, 0);
        }
        __syncthreads();
    }

    const int bb = r0 >> 10;
    const int s0 = r0 & 1023;

    if (ytile < 8) {
        const bool isQ = (ytile < 4);
        const float* bias = isQ ? bq : bk;
        unsigned short* dst = isQ ? Qb : Kb;
        const float scale = isQ ? 0.125f : 1.0f;
        const int h0 = cw >> 6;
        for (int mi = 0; mi < 4; mi++) {
            for (int ni = 0; ni < 4; ni++) {
                int col = wn * 64 + ni * 16 + l15;
                float bsv = bias[cw + col];
                for (int r = 0; r < 4; r++) {
                    int s_local = wm * 64 + mi * 16 + quad * 4 + r;
                    As[s_local * 136 + col] = f2bf((acc[mi][ni][r] + bsv) * scale);
                }
            }
        }
        __syncthreads();
        for (int p = 0; p < 2; p++) {
            size_t base = (((size_t)(bb * NHEAD + h0 + p)) << 10) + s0;
            for (int i = 0; i < 4; i++) {
                int flat = i * 256 + tid;
                int row = flat >> 3;
                int ch = flat & 7;
                uint4 vv = *reinterpret_cast<const uint4*>(As + row * 136 + p * 64 + ch * 8);
                *reinterpret_cast<uint4*>(dst + (base + row) * 64 + ch * 8) = vv;
            }
        }
    } else {
        const int h_base = (c0 - 1024) >> 6;
        for (int p = 0; p < 2; p++) {
            __syncthreads();
            if (wn == p) {
                for (int mi = 0; mi < 4; mi++) {
                    for (int ni = 0; ni < 4; ni++) {
                        int d_local = ni * 16 + l15;
                        float bias = bv[(h_base + p) * 64 + d_local];
                        for (int r = 0; r < 4; r++) {
                            int s_local = wm * 64 + mi * 16 + quad * 4 + r;
                            As[d_local * 136 + s_local] = f2bf(acc[mi][ni][r] + bias);
                        }
                    }
                }
            }
            __syncthreads();
            int sidx = (tid & 15) * 8;
            int drow = tid >> 4;
            for (int dg = 0; dg < 4; dg++) {
                int d = dg * 16 + drow;
                size_t dst = ((size_t)(bb * NHEAD + h_base + p) * 64 + d) * 1024 + s0;
                uint4 vv = *reinterpret_cast<const uint4*>(As + d * 136 + sidx);
                *reinterpret_cast<uint4*>(Vtb + dst + sidx) = vv;
            }
        }
    }
}

// ---------------- flash attention: 2-tile ILP + joint softmax + XCD swizzle ----------------
// Grid flat 2048: bh = flat&63 (keeps all q-blocks of one (b,h) on one XCD),
// qt = flat>>6. Wave (qsub,khalf) owns 16 q-rows x 512 keys, processed as
// 4 pairs of 64-key tiles: 16 K-loads + 16 V-loads in flight per pair; ONE
// joint online-softmax update per 128 keys. Wave pairs merge via LDS.
__global__ __launch_bounds__(256) void attn_kernel(
    const unsigned short* __restrict__ Qb,
    const unsigned short* __restrict__ Kb,
    const unsigned short* __restrict__ Vtb,
    const unsigned long long* __restrict__ Mbits,
    unsigned short* __restrict__ Ob)
{
    __shared__ __bf16 Ps[2 * 4 * 16 * 72];   // 18432 B (two P^T buffers); merge overlays

    const int tid = threadIdx.x;
    const int w = tid >> 6, lane = tid & 63, l15 = lane & 15, quad = lane >> 4;
    const int qsub = w >> 1, khalf = w & 1;
    const int flat = blockIdx.x;
    const int bh = flat & 63;
    const int qt = flat >> 6;
    const int b = bh >> 3, h = bh & 7;
    const int q = qt * 32 + qsub * 16 + l15;
    const unsigned short* Qg = Qb + (size_t)bh * SLEN * 64;
    const unsigned short* Kg = Kb + (size_t)bh * SLEN * 64;
    const unsigned short* Vg = Vtb + (size_t)bh * 64 * SLEN;
    const unsigned long long* mrow = Mbits + ((size_t)b * SLEN + q) * 16;
    __bf16* Prow0 = Ps + (w * 16 + l15) * 72;
    __bf16* Prow1 = Prow0 + 4608;

    bf16x8 bq0 = *reinterpret_cast<const bf16x8*>(Qg + (size_t)q * 64 + quad * 8);
    bf16x8 bq1 = *reinterpret_cast<const bf16x8*>(Qg + (size_t)q * 64 + 32 + quad * 8);

    float m_i = -3.0e38f, l_i = 0.0f;
    f32x4 zero = {0.0f, 0.0f, 0.0f, 0.0f};
    f32x4 Oacc[4];
    for (int nd = 0; nd < 4; nd++) Oacc[nd] = zero;

    for (int kpair = 0; kpair < 4; kpair++) {
        const int kta = khalf * 8 + kpair * 2;
        const int k0a = kta * 64, k0b = k0a + 64;

        unsigned long long mwa = mrow[kta] >> (quad * 4);
        unsigned long long mwb = mrow[kta + 1] >> (quad * 4);

        // S^T for both tiles (16 K loads in flight)
        f32x4 sa[4], sb[4];
        for (int ni = 0; ni < 4; ni++) {
            const unsigned short* kp = Kg + (size_t)(k0a + ni * 16 + l15) * 64 + quad * 8;
            bf16x8 ka0 = *reinterpret_cast<const bf16x8*>(kp);
            bf16x8 ka1 = *reinterpret_cast<const bf16x8*>(kp + 32);
            f32x4 z = zero;
            z = __builtin_amdgcn_mfma_f32_16x16x32_bf16(ka0, bq0, z, 0, 0, 0);
            z = __builtin_amdgcn_mfma_f32_16x16x32_bf16(ka1, bq1, z, 0, 0, 0);
            sa[ni] = z;
        }
        for (int ni = 0; ni < 4; ni++) {
            const unsigned short* kp = Kg + (size_t)(k0b + ni * 16 + l15) * 64 + quad * 8;
            bf16x8 kb0 = *reinterpret_cast<const bf16x8*>(kp);
            bf16x8 kb1 = *reinterpret_cast<const bf16x8*>(kp + 32);
            f32x4 z = zero;
            z = __builtin_amdgcn_mfma_f32_16x16x32_bf16(kb0, bq0, z, 0, 0, 0);
            z = __builtin_amdgcn_mfma_f32_16x16x32_bf16(kb1, bq1, z, 0, 0, 0);
            sb[ni] = z;
        }

        // V fragments for both tiles — issued BEFORE the softmax VALU chain
        bf16x8 va[4][2], vb[4][2];
        for (int nd = 0; nd < 4; nd++) {
            const unsigned short* vp = Vg + (size_t)(nd * 16 + l15) * SLEN + k0a + quad * 8;
            va[nd][0] = *reinterpret_cast<const bf16x8*>(vp);
            va[nd][1] = *reinterpret_cast<const bf16x8*>(vp + 32);
            const unsigned short* vp2 = Vg + (size_t)(nd * 16 + l15) * SLEN + k0b + quad * 8;
            vb[nd][0] = *reinterpret_cast<const bf16x8*>(vp2);
            vb[nd][1] = *reinterpret_cast<const bf16x8*>(vp2 + 32);
        }

        // mask both tiles
        {
            unsigned int lo = (unsigned int)mwa, hi = (unsigned int)(mwa >> 32);
            for (int r = 0; r < 4; r++) {
                sa[0][r] = ((lo >> r) & 1u)        ? -1.0e7f : sa[0][r];
                sa[1][r] = ((lo >> (16 + r)) & 1u) ? -1.0e7f : sa[1][r];
                sa[2][r] = ((hi >> r) & 1u)        ? -1.0e7f : sa[2][r];
                sa[3][r] = ((hi >> (16 + r)) & 1u) ? -1.0e7f : sa[3][r];
            }
        }
        {
            unsigned int lo = (unsigned int)mwb, hi = (unsigned int)(mwb >> 32);
            for (int r = 0; r < 4; r++) {
                sb[0][r] = ((lo >> r) & 1u)        ? -1.0e7f : sb[0][r];
                sb[1][r] = ((lo >> (16 + r)) & 1u) ? -1.0e7f : sb[1][r];
                sb[2][r] = ((hi >> r) & 1u)        ? -1.0e7f : sb[2][r];
                sb[3][r] = ((hi >> (16 + r)) & 1u) ? -1.0e7f : sb[3][r];
            }
        }

        // joint max over 128 keys (32 regs) + cross-quad combine
        float ta = fmaxf(fmaxf(fmaxf(sa[0][0], sa[0][1]), fmaxf(sa[0][2], sa[0][3])),
                         fmaxf(fmaxf(sa[1][0], sa[1][1]), fmaxf(sa[1][2], sa[1][3])));
        float tb = fmaxf(fmaxf(fmaxf(sa[2][0], sa[2][1]), fmaxf(sa[2][2], sa[2][3])),
                         fmaxf(fmaxf(sa[3][0], sa[3][1]), fmaxf(sa[3][2], sa[3][3])));
        float tc = fmaxf(fmaxf(fmaxf(sb[0][0], sb[0][1]), fmaxf(sb[0][2], sb[0][3])),
                         fmaxf(fmaxf(sb[1][0], sb[1][1]), fmaxf(sb[1][2], sb[1][3])));
        float td = fmaxf(fmaxf(fmaxf(sb[2][0], sb[2][1]), fmaxf(sb[2][2], sb[2][3])),
                         fmaxf(fmaxf(sb[3][0], sb[3][1]), fmaxf(sb[3][2], sb[3][3])));
        float t = fmaxf(fmaxf(ta, tb), fmaxf(tc, td));
        t = fmaxf(t, __shfl_xor(t, 16));
        t = fmaxf(t, __shfl_xor(t, 32));
        float mnew = fmaxf(m_i, t);
        float alpha = __expf(m_i - mnew);
        m_i = mnew;

        float psum = 0.0f;
        for (int ni = 0; ni < 4; ni++) {
            float p0 = __expf(sa[ni][0] - mnew);
            float p1 = __expf(sa[ni][1] - mnew);
            float p2 = __expf(sa[ni][2] - mnew);
            float p3 = __expf(sa[ni][3] - mnew);
            psum += (p0 + p1) + (p2 + p3);
            uint2 pk;
            pk.x = pack2(p0, p1);
            pk.y = pack2(p2, p3);
            *reinterpret_cast<uint2*>(Prow0 + ni * 16 + quad * 4) = pk;
        }
        for (int ni = 0; ni < 4; ni++) {
            float p0 = __expf(sb[ni][0] - mnew);
            float p1 = __expf(sb[ni][1] - mnew);
            float p2 = __expf(sb[ni][2] - mnew);
            float p3 = __expf(sb[ni][3] - mnew);
            psum += (p0 + p1) + (p2 + p3);
            uint2 pk;
            pk.x = pack2(p0, p1);
            pk.y = pack2(p2, p3);
            *reinterpret_cast<uint2*>(Prow1 + ni * 16 + quad * 4) = pk;
        }
        psum += __shfl_xor(psum, 16);
        psum += __shfl_xor(psum, 32);
        l_i = l_i * alpha + psum;
        for (int nd = 0; nd < 4; nd++)
            for (int r = 0; r < 4; r++)
                Oacc[nd][r] *= alpha;

        bf16x8 pa0 = *reinterpret_cast<const bf16x8*>(Prow0 + quad * 8);
        bf16x8 pa1 = *reinterpret_cast<const bf16x8*>(Prow0 + 32 + quad * 8);
        bf16x8 pb0 = *reinterpret_cast<const bf16x8*>(Prow1 + quad * 8);
        bf16x8 pb1 = *reinterpret_cast<const bf16x8*>(Prow1 + 32 + quad * 8);
        for (int nd = 0; nd < 4; nd++) {
            Oacc[nd] = __builtin_amdgcn_mfma_f32_16x16x32_bf16(va[nd][0], pa0, Oacc[nd], 0, 0, 0);
            Oacc[nd] = __builtin_amdgcn_mfma_f32_16x16x32_bf16(va[nd][1], pa1, Oacc[nd], 0, 0, 0);
            Oacc[nd] = __builtin_amdgcn_mfma_f32_16x16x32_bf16(vb[nd][0], pb0, Oacc[nd], 0, 0, 0);
            Oacc[nd] = __builtin_amdgcn_mfma_f32_16x16x32_bf16(vb[nd][1], pb1, Oacc[nd], 0, 0, 0);
        }
    }

    // ---- flash-decoding merge of the wave pair (khalf 0 <-> 1) ----
    float* Smerge = (float*)Ps;
    float* ML = Smerge;            // [w][lane][2]
    float* OB = Smerge + 512;      // [qsub][(nd*4+r)][lane]
    __syncthreads();
    ML[(w * 64 + lane) * 2 + 0] = m_i;
    ML[(w * 64 + lane) * 2 + 1] = l_i;
    __syncthreads();
    float mp = ML[((w ^ 1) * 64 + lane) * 2 + 0];
    float lp = ML[((w ^ 1) * 64 + lane) * 2 + 1];
    float m01 = fmaxf(m_i, mp);
    float e  = __expf(m_i - m01);
    float ep = __expf(mp - m01);
    float l01 = l_i * e + lp * ep;

    if (khalf == 1) {
        for (int nd = 0; nd < 4; nd++)
            for (int r = 0; r < 4; r++)
                OB[qsub * 1024 + (nd * 4 + r) * 64 + lane] = Oacc[nd][r] * e;
    }
    __syncthreads();
    if (khalf == 0) {
        float inv = 1.0f / l01;
        for (int nd = 0; nd < 4; nd++) {
            float o0 = (Oacc[nd][0] * e + OB[qsub * 1024 + (nd * 4 + 0) * 64 + lane]) * inv;
            float o1 = (Oacc[nd][1] * e + OB[qsub * 1024 + (nd * 4 + 1) * 64 + lane]) * inv;
            float o2 = (Oacc[nd][2] * e + OB[qsub * 1024 + (nd * 4 + 2) * 64 + lane]) * inv;
            float o3 = (Oacc[nd][3] * e + OB[qsub * 1024 + (nd * 4 + 3) * 64 + lane]) * inv;
            uint2 o;
            o.x = pack2(o0, o1);
            o.y = pack2(o2, o3);
            *reinterpret_cast<uint2*>(Ob + ((size_t)(b * SLEN + q)) * 512 + h * 64 + nd * 16 + quad * 4) = o;
        }
    }
}

// ---------------- output projection GEMM (bf16 in, f32 out, BK=64) ----------------
__global__ __launch_bounds__(256) void out_gemm(
    const unsigned short* __restrict__ Ob,
    const unsigned short* __restrict__ Wob,
    const float* __restrict__ bo,
    float* __restrict__ out)
{
    __shared__ unsigned short As[2 * 128 * 72];
    unsigned short* Bs = As + 128 * 72;
    const int tid = threadIdx.x;
    const int w = tid >> 6, lane = tid & 63, l15 = lane & 15, quad = lane >> 4;
    const int wm = w & 1, wn = w >> 1;
    const int r0 = blockIdx.x * 128;
    const int c0 = blockIdx.y * 128;

    f32x4 zero = {0.0f, 0.0f, 0.0f, 0.0f};
    f32x4 acc[4][4];
    for (int i = 0; i < 4; i++)
        for (int j = 0; j < 4; j++) acc[i][j] = zero;

    const int srow = tid >> 1;
    const int scol = (tid & 1) * 32;

    for (int k0 = 0; k0 < 512; k0 += 64) {
        const unsigned short* pa = Ob + (size_t)(r0 + srow) * 512 + k0 + scol;
        const unsigned short* pb = Wob + (size_t)(c0 + srow) * 512 + k0 + scol;
        uint4 a0 = *reinterpret_cast<const uint4*>(pa);
        uint4 a1 = *reinterpret_cast<const uint4*>(pa + 8);
        uint4 a2 = *reinterpret_cast<const uint4*>(pa + 16);
        uint4 a3 = *reinterpret_cast<const uint4*>(pa + 24);
        uint4 b0 = *reinterpret_cast<const uint4*>(pb);
        uint4 b1 = *reinterpret_cast<const uint4*>(pb + 8);
        uint4 b2 = *reinterpret_cast<const uint4*>(pb + 16);
        uint4 b3 = *reinterpret_cast<const uint4*>(pb + 24);
        unsigned short* wa = As + srow * 72 + scol;
        unsigned short* wb = Bs + srow * 72 + scol;
        *reinterpret_cast<uint4*>(wa) = a0;
        *reinterpret_cast<uint4*>(wa + 8) = a1;
        *reinterpret_cast<uint4*>(wa + 16) = a2;
        *reinterpret_cast<uint4*>(wa + 24) = a3;
        *reinterpret_cast<uint4*>(wb) = b0;
        *reinterpret_cast<uint4*>(wb + 8) = b1;
        *reinterpret_cast<uint4*>(wb + 16) = b2;
        *reinterpret_cast<uint4*>(wb + 24) = b3;
        __syncthreads();
        for (int kc = 0; kc < 64; kc += 32) {
            bf16x8 af[4], bfr[4];
            for (int mi = 0; mi < 4; mi++)
                af[mi] = *reinterpret_cast<const bf16x8*>(As + (wm * 64 + mi * 16 + l15) * 72 + kc + quad * 8);
            for (int ni = 0; ni < 4; ni++)
                bfr[ni] = *reinterpret_cast<const bf16x8*>(Bs + (wn * 64 + ni * 16 + l15) * 72 + kc + quad * 8);
            for (int mi = 0; mi < 4; mi++)
                for (int ni = 0; ni < 4; ni++)
                    acc[mi][ni] = __builtin_amdgcn_mfma_f32_16x16x32_bf16(af[mi], bfr[ni], acc[mi][ni], 0, 0, 0);
        }
        __syncthreads();
    }

    for (int mi = 0; mi < 4; mi++) {
        int grow_base = r0 + wm * 64 + mi * 16 + quad * 4;
        for (int ni = 0; ni < 4; ni++) {
            int gcol = c0 + wn * 64 + ni * 16 + l15;
            float bias = bo[gcol];
            for (int r = 0; r < 4; r++) {
                int grow = grow_base + r;
                out[(size_t)grow * 512 + gcol] = acc[mi][ni][r] + bias;
            }
        }
    }
}

extern "C" void kernel_launch(void* const* d_in, const int* in_sizes, int n_in,
                              void* d_out, int out_size, void* d_ws, size_t ws_size,
                              hipStream_t stream) {
    (void)in_sizes; (void)n_in; (void)out_size; (void)ws_size;
    const float* x    = (const float*)d_in[0];
    const float* mask = (const float*)d_in[1];
    const float* wq   = (const float*)d_in[2];
    const float* bq   = (const float*)d_in[3];
    const float* wk   = (const float*)d_in[4];
    const float* bk   = (const float*)d_in[5];
    const float* wv   = (const float*)d_in[6];
    const float* bv   = (const float*)d_in[7];
    const float* wo   = (const float*)d_in[8];
    const float* bo   = (const float*)d_in[9];
    float* out = (float*)d_out;

    char* ws = (char*)d_ws;
    unsigned short* Qb   = (unsigned short*)(ws);                  // 8 MiB
    unsigned short* Kb   = (unsigned short*)(ws + 8388608);        // 8 MiB
    unsigned short* Vtb  = (unsigned short*)(ws + 16777216);       // 8 MiB
    unsigned short* XO   = (unsigned short*)(ws + 25165824);       // 8 MiB: Xb then Obuf
    unsigned short* Wc   = (unsigned short*)(ws + 33554432);       // 2 MiB
    unsigned long long* Mbits = (unsigned long long*)(ws + 35651584); // 1 MiB

    pack_mask<<<8192, 256, 0, stream>>>(mask, Mbits);
    cast_all<<<dim3(2048, 5), 256, 0, stream>>>(x, wq, wk, wv, wo, XO, Wc);
    qkv_gemm<<<dim3(64, 12), 256, 0, stream>>>(XO, Wc, bq, bk, bv, Qb, Kb, Vtb);
    attn_kernel<<<dim3(2048), 256, 0, stream>>>(Qb, Kb, Vtb, Mbits, XO /*Obuf*/);
    out_gemm<<<dim3(64, 4), 256, 0, stream>>>(XO /*Obuf*/, Wc + 3 * 262144, bo, out);
}